// Round 1
// baseline (7223.546 us; speedup 1.0000x reference)
//
#include <hip/hip_runtime.h>

#define D_DIM 128

// ---------------------------------------------------------------------------
// Phase 1: scatter-add x[N,128] into pooled[S,128] via fp32 HW atomics.
// 32 threads per row; each thread handles a float4 (16B) chunk -> coalesced
// 512B/row reads. unsafeAtomicAdd emits global_atomic_add_f32 (no CAS loop).
// ---------------------------------------------------------------------------
__global__ __launch_bounds__(256) void scatter_add_kernel(
    const float* __restrict__ x,
    const int* __restrict__ idx,
    float* __restrict__ pooled,
    long long n_items) {
  long long stride = (long long)gridDim.x * blockDim.x;
  for (long long i = (long long)blockIdx.x * blockDim.x + threadIdx.x;
       i < n_items; i += stride) {
    long long row = i >> 5;          // 32 threads per row
    int q = ((int)i & 31) << 2;      // column offset (0,4,8,...,124)
    int s = idx[row];                // broadcast within the 32-lane group
    float4 v = *reinterpret_cast<const float4*>(&x[row * D_DIM + q]);
    float* dst = &pooled[(long long)s * D_DIM + q];
    unsafeAtomicAdd(dst + 0, v.x);
    unsafeAtomicAdd(dst + 1, v.y);
    unsafeAtomicAdd(dst + 2, v.z);
    unsafeAtomicAdd(dst + 3, v.w);
  }
}

// ---------------------------------------------------------------------------
// Phase 2: out[s][j] = b[j] + sum_d pooled[s][d] * W[j][d], done IN PLACE on
// the pooled buffer (== d_out). One wave per row; W transposed into LDS
// (Wt[d][j], 64KB). Each lane owns output cols {2*lane, 2*lane+1}; the row is
// loaded as float2 per lane and broadcast via __shfl. float2 LDS reads are
// 2-way bank aliasing across a wave64 = free.
// In-place safety: the full row is in registers (rv) before any write.
// ---------------------------------------------------------------------------
__global__ __launch_bounds__(256) void transform_kernel(
    float* data,                    // [S,128]: pooled in, out out
    const float* __restrict__ W,    // [128,128], row-major [out][in]
    const float* __restrict__ b,    // [128]
    int S) {
  __shared__ float Wt[D_DIM][D_DIM];   // Wt[d][j] = W[j][d]  (64 KB)
  int t = threadIdx.x;
  for (int f = t; f < D_DIM * D_DIM; f += 256) {
    Wt[f & (D_DIM - 1)][f >> 7] = W[f];   // coalesced global read
  }
  __syncthreads();

  int lane = t & 63;
  int wv = t >> 6;
  int waveGlobal = blockIdx.x * 4 + wv;
  int nWaves = gridDim.x * 4;
  float2 bb = *reinterpret_cast<const float2*>(&b[2 * lane]);

  for (int s = waveGlobal; s < S; s += nWaves) {
    float2 rv = *reinterpret_cast<const float2*>(&data[(long long)s * D_DIM + 2 * lane]);
    float accx = bb.x, accy = bb.y;
#pragma unroll
    for (int k = 0; k < 64; ++k) {
      float p0 = __shfl(rv.x, k);   // pooled[s][2k]
      float p1 = __shfl(rv.y, k);   // pooled[s][2k+1]
      float2 w0 = *reinterpret_cast<const float2*>(&Wt[2 * k][2 * lane]);
      float2 w1 = *reinterpret_cast<const float2*>(&Wt[2 * k + 1][2 * lane]);
      accx += p0 * w0.x + p1 * w1.x;
      accy += p0 * w0.y + p1 * w1.y;
    }
    float2 res = make_float2(accx, accy);
    *reinterpret_cast<float2*>(&data[(long long)s * D_DIM + 2 * lane]) = res;
  }
}

extern "C" void kernel_launch(void* const* d_in, const int* in_sizes, int n_in,
                              void* d_out, int out_size, void* d_ws, size_t ws_size,
                              hipStream_t stream) {
  // inputs: x [N*128] f32, dst_idx [N] int, dst_size [1] int, W [128*128] f32, b [128] f32
  const float* x = (const float*)d_in[0];
  const int* idx = (const int*)d_in[1];
  const float* W = (const float*)d_in[3];
  const float* b = (const float*)d_in[4];
  float* out = (float*)d_out;

  long long N = (long long)in_sizes[0] / D_DIM;
  int S = out_size / D_DIM;

  // zero the accumulator (d_out doubles as pooled buffer)
  hipMemsetAsync(d_out, 0, (size_t)out_size * sizeof(float), stream);

  long long n_items = N * 32;  // 32 threads per row
  scatter_add_kernel<<<2048, 256, 0, stream>>>(x, idx, out, n_items);
  transform_kernel<<<2048, 256, 0, stream>>>(out, W, b, S);
}

// Round 2
// 1442.380 us; speedup vs baseline: 5.0081x; 5.0081x over previous
//
#include <hip/hip_runtime.h>

#define D_DIM 128

// ---------------------------------------------------------------------------
// K1: histogram of segment ids. 4.19M int atomics (random over 64K counters).
// ---------------------------------------------------------------------------
__global__ __launch_bounds__(256) void hist_kernel(
    const int* __restrict__ idx, int* __restrict__ cnt, int n) {
  int stride = gridDim.x * blockDim.x;
  for (int i = blockIdx.x * blockDim.x + threadIdx.x; i < n; i += stride)
    atomicAdd(&cnt[idx[i]], 1);
}

// ---------------------------------------------------------------------------
// K2a/K2b/K2c: hierarchical exclusive scan of cnt[S] (S = 65536 -> 256 blocks
// of 256). After K2c, cnt[s] = exclusive prefix (start offset of segment s).
// ---------------------------------------------------------------------------
__global__ __launch_bounds__(256) void scan_local_kernel(
    int* data, int* sums, int S) {
  __shared__ int sd[256];
  int t = threadIdx.x;
  int i = blockIdx.x * 256 + t;
  int v = (i < S) ? data[i] : 0;
  sd[t] = v;
  __syncthreads();
  for (int off = 1; off < 256; off <<= 1) {
    int u = (t >= off) ? sd[t - off] : 0;
    __syncthreads();
    sd[t] += u;
    __syncthreads();
  }
  if (i < S) data[i] = sd[t] - v;          // block-local exclusive
  if (t == 255) sums[blockIdx.x] = sd[255];  // block total
}

__global__ __launch_bounds__(256) void scan_sums_kernel(int* sums, int nb) {
  __shared__ int sd[256];
  int t = threadIdx.x;
  int v = (t < nb) ? sums[t] : 0;
  sd[t] = v;
  __syncthreads();
  for (int off = 1; off < 256; off <<= 1) {
    int u = (t >= off) ? sd[t - off] : 0;
    __syncthreads();
    sd[t] += u;
    __syncthreads();
  }
  if (t < nb) sums[t] = sd[t] - v;  // exclusive block offsets
}

__global__ __launch_bounds__(256) void scan_add_kernel(
    int* data, const int* __restrict__ sums, int S) {
  int i = blockIdx.x * 256 + threadIdx.x;
  if (i < S) data[i] += sums[blockIdx.x];
}

// ---------------------------------------------------------------------------
// K3: scatter row ids into segment-sorted order. Advances cnt[s] in place:
// post-K3, cnt[s] == original exclusive offset of segment s+1 (i.e. end of s).
// ---------------------------------------------------------------------------
__global__ __launch_bounds__(256) void scatter_idx_kernel(
    const int* __restrict__ idx, int* cnt, int* __restrict__ rowids, int n) {
  int stride = gridDim.x * blockDim.x;
  for (int i = blockIdx.x * blockDim.x + threadIdx.x; i < n; i += stride) {
    int pos = atomicAdd(&cnt[idx[i]], 1);
    rowids[pos] = i;
  }
}

// ---------------------------------------------------------------------------
// K4: fused gather-reduce + linear transform. One wave per segment.
// - rowids for the segment loaded 64-at-a-time (coalesced), broadcast by shfl
// - each row read as float2/lane (512B contiguous per row), 4 rows unrolled
//   for 4 outstanding VMEM per wave (x16 waves/CU -> HBM saturation)
// - transform: Wt (W transposed) in LDS, padded stride 129 to keep the
//   fill conflict-free; row broadcast via shfl, out written once.
// post-K3 cnt[] gives [start,end): start = cnt[s-1] (0 for s=0), end = cnt[s].
// ---------------------------------------------------------------------------
__global__ __launch_bounds__(512) void gather_transform_kernel(
    const float* __restrict__ x,
    const int* __restrict__ rowids,
    const int* __restrict__ cnt,      // post-scatter offsets (end of each seg)
    const float* __restrict__ W,      // [128,128] row-major [out][in]
    const float* __restrict__ b,      // [128]
    float* __restrict__ out,          // [S,128]
    int S) {
  __shared__ float Wt[D_DIM][D_DIM + 1];  // Wt[d][j] = W[j][d], padded
  int t = threadIdx.x;
  for (int f = t; f < D_DIM * D_DIM; f += 512) {
    Wt[f & (D_DIM - 1)][f >> 7] = W[f];   // coalesced global, conflict-free LDS
  }
  __syncthreads();

  int lane = t & 63;
  int wv = t >> 6;
  float2 bb = *reinterpret_cast<const float2*>(&b[2 * lane]);
  int nW = gridDim.x * 8;

  for (int s = blockIdx.x * 8 + wv; s < S; s += nW) {
    int start = (s == 0) ? 0 : cnt[s - 1];
    int end = cnt[s];
    float ax = 0.f, ay = 0.f;

    for (int base = start; base < end; base += 64) {
      int m = end - base;
      int rid = 0;
      if (lane < m) rid = rowids[base + lane];
      int c = m < 64 ? m : 64;
      int j = 0;
      for (; j + 4 <= c; j += 4) {
        int r0 = __shfl(rid, j);
        int r1 = __shfl(rid, j + 1);
        int r2 = __shfl(rid, j + 2);
        int r3 = __shfl(rid, j + 3);
        float2 v0 = *reinterpret_cast<const float2*>(x + (((long long)r0) << 7) + 2 * lane);
        float2 v1 = *reinterpret_cast<const float2*>(x + (((long long)r1) << 7) + 2 * lane);
        float2 v2 = *reinterpret_cast<const float2*>(x + (((long long)r2) << 7) + 2 * lane);
        float2 v3 = *reinterpret_cast<const float2*>(x + (((long long)r3) << 7) + 2 * lane);
        ax += v0.x + v1.x + v2.x + v3.x;
        ay += v0.y + v1.y + v2.y + v3.y;
      }
      for (; j < c; ++j) {
        int r = __shfl(rid, j);
        float2 v = *reinterpret_cast<const float2*>(x + (((long long)r) << 7) + 2 * lane);
        ax += v.x;
        ay += v.y;
      }
    }

    // transform: out[s][j] = b[j] + sum_d pooled[d] * W[j][d]
    float ox = bb.x, oy = bb.y;
#pragma unroll
    for (int k = 0; k < 64; ++k) {
      float p0 = __shfl(ax, k);   // pooled[2k]
      float p1 = __shfl(ay, k);   // pooled[2k+1]
      float2 w0 = *reinterpret_cast<const float2*>(&Wt[2 * k][2 * lane]);
      float2 w1 = *reinterpret_cast<const float2*>(&Wt[2 * k + 1][2 * lane]);
      ox += p0 * w0.x + p1 * w1.x;
      oy += p0 * w0.y + p1 * w1.y;
    }
    *reinterpret_cast<float2*>(&out[(long long)s * D_DIM + 2 * lane]) =
        make_float2(ox, oy);
  }
}

extern "C" void kernel_launch(void* const* d_in, const int* in_sizes, int n_in,
                              void* d_out, int out_size, void* d_ws, size_t ws_size,
                              hipStream_t stream) {
  const float* x = (const float*)d_in[0];
  const int* idx = (const int*)d_in[1];
  const float* W = (const float*)d_in[3];
  const float* b = (const float*)d_in[4];
  float* out = (float*)d_out;

  int N = in_sizes[0] / D_DIM;
  int S = out_size / D_DIM;
  int nb = (S + 255) / 256;  // 256 for S=65536

  // ws layout: cnt[S] | sums[256] | rowids[N]
  int* cnt = (int*)d_ws;
  int* sums = cnt + S;
  int* rowids = sums + 256;

  hipMemsetAsync(d_ws, 0, (size_t)(S + 256) * sizeof(int), stream);

  hist_kernel<<<4096, 256, 0, stream>>>(idx, cnt, N);
  scan_local_kernel<<<nb, 256, 0, stream>>>(cnt, sums, S);
  scan_sums_kernel<<<1, 256, 0, stream>>>(sums, nb);
  scan_add_kernel<<<nb, 256, 0, stream>>>(cnt, sums, S);
  scatter_idx_kernel<<<4096, 256, 0, stream>>>(idx, cnt, rowids, N);
  gather_transform_kernel<<<2048, 512, 0, stream>>>(x, rowids, cnt, W, b, out, S);
}